// Round 7
// baseline (2316.097 us; speedup 1.0000x reference)
//
#include <hip/hip_runtime.h>

typedef __bf16 bf16x8 __attribute__((ext_vector_type(8)));
typedef float f32x4 __attribute__((ext_vector_type(4)));
typedef float f32x16 __attribute__((ext_vector_type(16)));

#define MFMA16(a, b, c) __builtin_amdgcn_mfma_f32_16x16x32_bf16(a, b, c, 0, 0, 0)
#define MFMA32(a, b, c) __builtin_amdgcn_mfma_f32_32x32x16_bf16(a, b, c, 0, 0, 0)
#define LOG2E 1.44269504088896340736f

__device__ __forceinline__ unsigned short f2bf(float f) {
  union { float f; unsigned u; } v; v.f = f;
  return (unsigned short)((v.u + 0x7fffu + ((v.u >> 16) & 1u)) >> 16);
}
__device__ __forceinline__ bf16x8 ld_frag(const unsigned short* p) {
  return *(const bf16x8*)p;  // 16B-aligned by construction
}
__device__ __forceinline__ void gld_lds16(const unsigned short* g, unsigned short* l) {
  __builtin_amdgcn_global_load_lds(
      (const __attribute__((address_space(1))) unsigned int*)(const void*)g,
      (__attribute__((address_space(3))) unsigned int*)(void*)l, 16, 0, 0);
}
// LDS-visibility barrier (lgkmcnt only; vmcnt stays outstanding)
__device__ __forceinline__ void bar_lds() {
  asm volatile("s_waitcnt lgkmcnt(0)\ns_barrier" ::: "memory");
}

// fp32 -> bf16, 4 elements/thread
__global__ void cvt_f2bf(const float* __restrict__ in,
                         unsigned short* __restrict__ out, int n4) {
  int i = blockIdx.x * blockDim.x + threadIdx.x;
  if (i < n4) {
    float4 v = ((const float4*)in)[i];
    ushort4 o;
    o.x = f2bf(v.x); o.y = f2bf(v.y); o.z = f2bf(v.z); o.w = f2bf(v.w);
    ((ushort4*)out)[i] = o;
  }
}

// ---------------------------------------------------------------------------
// C[M,N] = A[M,K] * B[N,K]^T + bias[N]   (A,B bf16; bias fp32)
// mode 0: store fp32 to outf[M,N]
// mode 1: QKV split: n<512 -> qbuf; n<1024 -> kbuf; else transposed vtbuf[b][d][s]
// ---------------------------------------------------------------------------
__global__ void gemm_bt(const unsigned short* __restrict__ A,
                        const unsigned short* __restrict__ B,
                        const float* __restrict__ bias,
                        float* __restrict__ outf,
                        unsigned short* __restrict__ qbuf,
                        unsigned short* __restrict__ kbuf,
                        unsigned short* __restrict__ vtbuf,
                        int M, int N, int K, int mode) {
  __shared__ alignas(16) unsigned short As[128 * 32];
  __shared__ alignas(16) unsigned short Bs[128 * 32];
  const int n0 = blockIdx.x * 128, m0 = blockIdx.y * 128;
  const int tid = threadIdx.x;
  const int l = tid & 63, w = tid >> 6;
  const int quad = l >> 4, c = l & 15;
  const int wm = (w >> 1) * 64, wn = (w & 1) * 64;

  f32x4 acc[4][4] = {};
  const int kiters = K >> 5;
  for (int kt = 0; kt < kiters; ++kt) {
    __syncthreads();
    const int kk = kt * 32 + (l & 3) * 8;
    const int row = l >> 2;
#pragma unroll
    for (int i = 0; i < 2; ++i) {
      const int rbase = i * 64 + w * 16;
      gld_lds16(&A[(size_t)(m0 + rbase + row) * K + kk], &As[rbase * 32]);
      gld_lds16(&B[(size_t)(n0 + rbase + row) * K + kk], &Bs[rbase * 32]);
    }
    __syncthreads();
    bf16x8 af[4], bfr[4];
#pragma unroll
    for (int t = 0; t < 4; ++t) {
      af[t] = ld_frag(&As[(wm + t * 16 + c) * 32 + quad * 8]);
      bfr[t] = ld_frag(&Bs[(wn + t * 16 + c) * 32 + quad * 8]);
    }
#pragma unroll
    for (int mt = 0; mt < 4; ++mt)
#pragma unroll
      for (int nt = 0; nt < 4; ++nt)
        acc[mt][nt] = MFMA16(af[mt], bfr[nt], acc[mt][nt]);
  }

#pragma unroll
  for (int nt = 0; nt < 4; ++nt) {
    const int n = n0 + wn + nt * 16 + c;
    const float bsum = bias[n];
#pragma unroll
    for (int mt = 0; mt < 4; ++mt) {
      const int mbase = m0 + wm + mt * 16 + quad * 4;
      if (mode == 0) {
#pragma unroll
        for (int r = 0; r < 4; ++r)
          outf[(size_t)(mbase + r) * N + n] = acc[mt][nt][r] + bsum;
      } else if (n < 1024) {
        unsigned short* dst = (n < 512) ? qbuf : kbuf;
        const int nn = n & 511;
#pragma unroll
        for (int r = 0; r < 4; ++r)
          dst[(size_t)(mbase + r) * 512 + nn] = f2bf(acc[mt][nt][r] + bsum);
      } else {
        const int d = n - 1024;
        const int bb = mbase >> 12, s = mbase & 4095;
        ushort4 pk;
        pk.x = f2bf(acc[mt][nt][0] + bsum);
        pk.y = f2bf(acc[mt][nt][1] + bsum);
        pk.z = f2bf(acc[mt][nt][2] + bsum);
        pk.w = f2bf(acc[mt][nt][3] + bsum);
        *(ushort4*)&vtbuf[((size_t)bb * 512 + d) * 4096 + s] = pk;
      }
    }
  }
}

// ---------------------------------------------------------------------------
// Flash attention, 32x32x16 MFMA, transposed-S, kv-split-2, LDS-staged.
// Grid 512 = (b,half)->XCD x 64 qt. Block 64 q x 2048 kv (64 iters of 32).
// Waves (qg,kh): QK^T partial over k-half (qf pinned 64 VGPR, kf rolled),
// f32 exchange overlaid on dead k_lds. PV: wave owns 128 d x all 64 q,
// o[4][2] f32x16 = 128 AGPR. 2 blocks/CU; LDS ~71 KB.
// ---------------------------------------------------------------------------
#define KROW 520
#define PROW 40
#define EXROW 20

__global__ __launch_bounds__(256, 2) void attn_kernel(
    const unsigned short* __restrict__ Q, const unsigned short* __restrict__ Kb,
    const unsigned short* __restrict__ Vt, unsigned short* __restrict__ part0,
    unsigned short* __restrict__ part1, float2* __restrict__ mlbuf) {
  __shared__ alignas(16) unsigned short k_lds[32 * KROW];   // 33.3 KB (+ex overlay)
  __shared__ alignas(16) unsigned short v_lds[512 * 32];    // 32 KB
  __shared__ alignas(16) unsigned short p_lds[2 * 32 * PROW];  // 5 KB
  __shared__ float alpha_lds[64];
  __shared__ float l_lds[64];

  const int bid = blockIdx.x;
  const int xcd = bid & 7;
  const int b = xcd >> 1;        // (b, half) pinned to one XCD: 4 MB K+V half fits L2
  const int half = xcd & 1;
  const int qt = bid >> 3;       // 0..63
  const int s0 = qt * 64;
  const int kvbase = half * 2048;
  const int tid = threadIdx.x;
  const int l = tid & 63, w = tid >> 6;
  const int qg = w >> 1, kh = w & 1;
  const int l31 = l & 31, h = l >> 5;
  const size_t boff = (size_t)b * 4096 * 512;

  // Q frags pinned: B-operand, q = s0+qg*32+l31, k = kh*256 + t*16 + h*8 + j
  bf16x8 qf[16];
  {
    const unsigned short* qrow =
        Q + boff + (size_t)(s0 + qg * 32 + l31) * 512 + kh * 256 + h * 8;
#pragma unroll
    for (int t = 0; t < 16; ++t) qf[t] = ld_frag(&qrow[t * 16]);
  }

  // O^T: [dt][g2]: d = w*128 + dt*32 + 8g + 4h + (0..3), q = g2*32 + l31
  f32x16 o[4][2] = {};
  float m_run = -3e38f, l_run = 0.f;  // own-qg softmax state, lane q = l31

  const unsigned short* Kbase = Kb + boff;
  const unsigned short* Vbase = Vt + (size_t)b * 512 * 4096;
  float* exf = (float*)k_lds;  // exchange overlay: 4*64*EXROW*4 = 20.5 KB < 33.3

  const float C1 = 0.125f * LOG2E;

  for (int it = 0; it < 64; ++it) {
    __syncthreads();  // b1: all prev-iter LDS reads done -> buffers reusable
    {
      const int kv0 = kvbase + it * 32;
#pragma unroll
      for (int i = 0; i < 8; ++i) {  // K: rows of 512 (1 KB each)
        const int row = i * 4 + w;
        gld_lds16(&Kbase[(size_t)(kv0 + row) * 512 + l * 8], &k_lds[row * KROW]);
      }
#pragma unroll
      for (int i = 0; i < 8; ++i) {  // Vt: XOR-swizzled kv-chunks
        const int dbase = (i * 4 + w) * 16;
        const int d = dbase + (l >> 2);
        const int jl = (l & 3) ^ ((d >> 1) & 3);
        gld_lds16(&Vbase[(size_t)d * 4096 + kv0 + jl * 8], &v_lds[dbase * 32]);
      }
    }
    __syncthreads();  // b2: staging drained (vmcnt0)

    // S^T partial over k-half kh: A = K[kv=l31][k], B = Q frag. kf rolled 2x.
    f32x16 a0 = {}, a1 = {};
    {
      const unsigned short* krow = &k_lds[l31 * KROW + kh * 256 + h * 8];
#pragma unroll
      for (int t = 0; t < 16; t += 2) {
        bf16x8 kf0 = ld_frag(&krow[t * 16]);
        bf16x8 kf1 = ld_frag(&krow[t * 16 + 16]);
        a0 = MFMA32(kf0, qf[t], a0);
        a1 = MFMA32(kf1, qf[t + 1], a1);
      }
    }
    f32x16 ss = a0 + a1;
    bar_lds();  // b3: all k_lds frag reads done (ex overlays k_lds)

    // exchange S-partial with k-half partner (w^1)
    {
      float* exw = &exf[(w * 64 + l) * EXROW];
#pragma unroll
      for (int g = 0; g < 4; ++g) {
        f32x4 t4;
        t4[0] = ss[g * 4]; t4[1] = ss[g * 4 + 1];
        t4[2] = ss[g * 4 + 2]; t4[3] = ss[g * 4 + 3];
        *(f32x4*)&exw[g * 4] = t4;
      }
    }
    bar_lds();  // b4: partials visible
    {
      const float* exp_ = &exf[((w ^ 1) * 64 + l) * EXROW];
#pragma unroll
      for (int g = 0; g < 4; ++g) {
        f32x4 t4 = *(const f32x4*)&exp_[g * 4];
        ss[g * 4] += t4[0]; ss[g * 4 + 1] += t4[1];
        ss[g * 4 + 2] += t4[2]; ss[g * 4 + 3] += t4[3];
      }
    }

    // softmax for own qg: lane holds 16 kv (rows 8g+4h+0..3) of 32; 1 shuffle
    float mloc = ss[0];
#pragma unroll
    for (int r = 1; r < 16; ++r) mloc = fmaxf(mloc, ss[r]);
    mloc = fmaxf(mloc, __shfl_xor(mloc, 32));
    const float mn = fmaxf(m_run, mloc);

    float s8 = 0.f;
#pragma unroll
    for (int r = 0; r < 16; ++r) {
      ss[r] = exp2f((ss[r] - mn) * C1);  // p in place
      s8 += ss[r];
    }
    s8 += __shfl_xor(s8, 32);
    const float a_own = exp2f((m_run - mn) * C1);  // 1.0 if max unchanged
    l_run = l_run * a_own + s8;
    m_run = mn;

    if (kh == 0) {  // one wave per qg publishes P^T and alpha
      unsigned short* pr = &p_lds[(qg * 32 + l31) * PROW + 4 * h];
#pragma unroll
      for (int g = 0; g < 4; ++g) {
        ushort4 u;
        u.x = f2bf(ss[g * 4]); u.y = f2bf(ss[g * 4 + 1]);
        u.z = f2bf(ss[g * 4 + 2]); u.w = f2bf(ss[g * 4 + 3]);
        *(ushort4*)&pr[8 * g] = u;  // kv = 8g + 4h + 0..3
      }
      if (h == 0) alpha_lds[qg * 32 + l31] = a_own;
    }
    bar_lds();  // b5: P^T + alpha visible

    // rescale o (both q-groups), then O^T += V^T P^T
    const float a_oth = alpha_lds[(qg ^ 1) * 32 + l31];
    if (__any(a_own < 1.f || a_oth < 1.f)) {
#pragma unroll
      for (int dt = 0; dt < 4; ++dt)
#pragma unroll
        for (int e = 0; e < 16; ++e) {
          o[dt][qg][e] *= a_own;
          o[dt][qg ^ 1][e] *= a_oth;
        }
    }

    bf16x8 pf[2][2];  // [g2][kvc]
#pragma unroll
    for (int g2 = 0; g2 < 2; ++g2)
#pragma unroll
      for (int kvc = 0; kvc < 2; ++kvc)
        pf[g2][kvc] =
            ld_frag(&p_lds[(g2 * 32 + l31) * PROW + kvc * 16 + h * 8]);
#pragma unroll
    for (int dt = 0; dt < 4; ++dt) {
      const int d = w * 128 + dt * 32 + l31;
      const int sw = (d >> 1) & 3;
      bf16x8 vf0 = ld_frag(&v_lds[d * 32 + ((0 + h) ^ sw) * 8]);  // kvc 0
      bf16x8 vf1 = ld_frag(&v_lds[d * 32 + ((2 + h) ^ sw) * 8]);  // kvc 1
      o[dt][0] = MFMA32(vf0, pf[0][0], o[dt][0]);
      o[dt][1] = MFMA32(vf0, pf[1][0], o[dt][1]);
      o[dt][0] = MFMA32(vf1, pf[0][1], o[dt][0]);
      o[dt][1] = MFMA32(vf1, pf[1][1], o[dt][1]);
    }
  }

  // epilogue: need l for the other q-group too
  if (kh == 0 && h == 0) l_lds[qg * 32 + l31] = l_run;
  bar_lds();
  const float invs[2] = {1.0f / l_lds[l31], 1.0f / l_lds[32 + l31]};

  unsigned short* part = half ? part1 : part0;
#pragma unroll
  for (int g2 = 0; g2 < 2; ++g2) {
    unsigned short* orow =
        part + boff + (size_t)(s0 + g2 * 32 + l31) * 512 + w * 128 + 4 * h;
    const float inv = invs[g2];
#pragma unroll
    for (int dt = 0; dt < 4; ++dt)
#pragma unroll
      for (int g = 0; g < 4; ++g) {
        ushort4 pk;
        pk.x = f2bf(o[dt][g2][g * 4 + 0] * inv);
        pk.y = f2bf(o[dt][g2][g * 4 + 1] * inv);
        pk.z = f2bf(o[dt][g2][g * 4 + 2] * inv);
        pk.w = f2bf(o[dt][g2][g * 4 + 3] * inv);
        *(ushort4*)&orow[dt * 32 + g * 8] = pk;
      }
  }
  if (kh == 0 && h == 0) {
    float2 ml; ml.x = m_run; ml.y = l_run;
    mlbuf[(size_t)half * 16384 + b * 4096 + s0 + qg * 32 + l31] = ml;
  }
}

// ---------------------------------------------------------------------------
// Merge the two kv-half streams: out = w0*P0 + w1*P1, w_h = l_h*2^((m_h-M)*C1)
// ---------------------------------------------------------------------------
__global__ void merge_halves(const unsigned short* __restrict__ p1,
                             const float2* __restrict__ mlbuf,
                             unsigned short* __restrict__ p0out) {
  const int i = blockIdx.x * blockDim.x + threadIdx.x;  // one per 8 elems
  const int row = i >> 6;
  const float2 a = mlbuf[row];
  const float2 bb = mlbuf[16384 + row];
  const float C1 = 0.125f * LOG2E;
  const float M = fmaxf(a.x, bb.x);
  float w0 = a.y * exp2f((a.x - M) * C1);
  float w1 = bb.y * exp2f((bb.x - M) * C1);
  const float inv = 1.0f / (w0 + w1);
  w0 *= inv; w1 *= inv;
  bf16x8 v0 = *(const bf16x8*)(p0out + (size_t)i * 8);
  bf16x8 v1 = *(const bf16x8*)(p1 + (size_t)i * 8);
  ushort4 o0, o1;
  o0.x = f2bf(w0 * (float)v0[0] + w1 * (float)v1[0]);
  o0.y = f2bf(w0 * (float)v0[1] + w1 * (float)v1[1]);
  o0.z = f2bf(w0 * (float)v0[2] + w1 * (float)v1[2]);
  o0.w = f2bf(w0 * (float)v0[3] + w1 * (float)v1[3]);
  o1.x = f2bf(w0 * (float)v0[4] + w1 * (float)v1[4]);
  o1.y = f2bf(w0 * (float)v0[5] + w1 * (float)v1[5]);
  o1.z = f2bf(w0 * (float)v0[6] + w1 * (float)v1[6]);
  o1.w = f2bf(w0 * (float)v0[7] + w1 * (float)v1[7]);
  *(ushort4*)(p0out + (size_t)i * 8) = o0;
  *(ushort4*)(p0out + (size_t)i * 8 + 4) = o1;
}

// ---------------------------------------------------------------------------
extern "C" void kernel_launch(void* const* d_in, const int* in_sizes, int n_in,
                              void* d_out, int out_size, void* d_ws, size_t ws_size,
                              hipStream_t stream) {
  const float* x = (const float*)d_in[0];      // [4,4096,512] fp32
  const float* w_in = (const float*)d_in[1];   // [1536,512] fp32
  const float* b_in = (const float*)d_in[2];   // [1536] fp32
  const float* w_out = (const float*)d_in[3];  // [512,512] fp32
  const float* b_out = (const float*)d_in[4];  // [512] fp32
  float* out = (float*)d_out;                  // [4,4096,512] fp32

  const size_t MTOT = (size_t)4 * 4096 * 512;  // 8,388,608
  unsigned short* q = (unsigned short*)d_ws;
  unsigned short* k = q + MTOT;
  unsigned short* vt = k + MTOT;       // [b][d][s]
  unsigned short* xbf = vt + MTOT;     // x bf16 -> attn part0 -> merged ao
  unsigned short* part1 = xbf + MTOT;  // attn part1
  unsigned short* w_in_bf = part1 + MTOT;
  unsigned short* w_out_bf = w_in_bf + 1536 * 512;
  float2* mlbuf = (float2*)(w_out_bf + 512 * 512);  // 2 x 16384 float2

  cvt_f2bf<<<dim3((int)(MTOT / 4 / 256)), 256, 0, stream>>>(x, xbf,
                                                            (int)(MTOT / 4));
  cvt_f2bf<<<dim3(768), 256, 0, stream>>>(w_in, w_in_bf, 1536 * 512 / 4);
  cvt_f2bf<<<dim3(256), 256, 0, stream>>>(w_out, w_out_bf, 512 * 512 / 4);

  gemm_bt<<<dim3(12, 128), 256, 0, stream>>>(xbf, w_in_bf, b_in, nullptr, q, k,
                                             vt, 16384, 1536, 512, 1);
  attn_kernel<<<dim3(512), 256, 0, stream>>>(q, k, vt, xbf, part1, mlbuf);
  merge_halves<<<dim3(4096), 256, 0, stream>>>(part1, mlbuf, xbf);
  gemm_bt<<<dim3(4, 128), 256, 0, stream>>>(xbf, w_out_bf, b_out, out, nullptr,
                                            nullptr, nullptr, 16384, 512, 512,
                                            0);
}